// Round 2
// baseline (1483.105 us; speedup 1.0000x reference)
//
#include <hip/hip_runtime.h>
#include <hip/hip_bf16.h>

#define NN 50000
#define EE 800000
#define GG 64
#define LL 3
#define CC 4
#define HH 64
#define BN_EPS 1e-5f
#define NSHADOW 16

// NOTE: harness passes ALL integer inputs as int32 (edge_index/batch included).

// ---------------- setup kernels ----------------

__global__ void k_deg(const int* __restrict__ dst, int* __restrict__ deg) {
    int e = blockIdx.x * blockDim.x + threadIdx.x;
    if (e < EE) atomicAdd(&deg[dst[e]], 1);
}

__global__ void k_clist(const int* __restrict__ labels, int* __restrict__ ccount,
                        int* __restrict__ clist) {
    int i = blockIdx.x * blockDim.x + threadIdx.x;
    if (i < NN) {
        int c = labels[i];
        int pos = atomicAdd(&ccount[c], 1);
        clist[c * NN + pos] = i;
    }
}

__global__ __launch_bounds__(1024) void k_scan(const int* __restrict__ deg,
                                               int* __restrict__ rowptr,
                                               int* __restrict__ cursor) {
    __shared__ int tot[1024];
    int t = threadIdx.x;
    const int CH = (NN + 1023) / 1024;  // 49
    int lo = t * CH;
    int hi = min(lo + CH, NN);
    int s = 0;
    for (int i = lo; i < hi; i++) s += deg[i];
    tot[t] = s;
    __syncthreads();
    if (t == 0) {
        int run = 0;
        for (int i = 0; i < 1024; i++) { int v = tot[i]; tot[i] = run; run += v; }
    }
    __syncthreads();
    int run = tot[t];
    for (int i = lo; i < hi; i++) { rowptr[i] = run; cursor[i] = run; run += deg[i]; }
    if (t == 1023) rowptr[NN] = run;  // == EE
}

__global__ void k_fill(const int* __restrict__ src, const int* __restrict__ dst,
                       int* __restrict__ cursor, int* __restrict__ adj) {
    int e = blockIdx.x * blockDim.x + threadIdx.x;
    if (e < EE) {
        int d = dst[e];
        int pos = atomicAdd(&cursor[d], 1);
        adj[pos] = src[e];
    }
}

// ---------------- per-(t,c) kernels ----------------
// Kernel A: agg (CSR gather) + h = agg + x, h1 = h@W1 + b1; store h1; accumulate BN stats.
__global__ __launch_bounds__(256) void k_gin_a(
    const float* __restrict__ xw, const int* __restrict__ adj,
    const int* __restrict__ rowptr, const int* __restrict__ clist_c,
    const int* __restrict__ ccount_c, const float* __restrict__ W1,
    const float* __restrict__ b1, float* __restrict__ h1buf,
    float* __restrict__ bnacc) {
    __shared__ float lds_bn[128];
    int cnt = *ccount_c;
    if ((int)blockIdx.x * 4 >= cnt) return;  // whole block inactive (uniform)
    int lane = threadIdx.x & 63;
    int wave = threadIdx.x >> 6;
    if (threadIdx.x < 128) lds_bn[threadIdx.x] = 0.f;
    __syncthreads();
    int idx = blockIdx.x * 4 + wave;
    if (idx < cnt) {
        int node = clist_c[idx];
        int rb = rowptr[node], re = rowptr[node + 1];
        float acc = xw[node * 64 + lane];
        for (int p = rb; p < re; p++) {
            int nb = adj[p];
            acc += xw[nb * 64 + lane];
        }
        // h1[lane] = b1[lane] + sum_j h[j] * W1[j][lane]  (h[j] broadcast via shfl)
        float s = b1[lane];
        #pragma unroll
        for (int j = 0; j < 64; j++) {
            s += __shfl(acc, j) * W1[j * 64 + lane];
        }
        h1buf[idx * 64 + lane] = s;
        atomicAdd(&lds_bn[lane], s);
        atomicAdd(&lds_bn[64 + lane], s * s);
    }
    __syncthreads();
    if (threadIdx.x < 128) {
        atomicAdd(&bnacc[(blockIdx.x & (NSHADOW - 1)) * 128 + threadIdx.x], lds_bn[threadIdx.x]);
    }
}

// Kernel C: scale/shift from BN stats; h1n = relu(bn(h1)); h2 = h1n@W2 + b2; x[node] = h2.
__global__ __launch_bounds__(256) void k_gin_c(
    float* __restrict__ xw, const int* __restrict__ clist_c,
    const int* __restrict__ ccount_c, const float* __restrict__ g1,
    const float* __restrict__ be1, const float* __restrict__ W2,
    const float* __restrict__ b2, const float* __restrict__ h1buf,
    const float* __restrict__ bnacc) {
    __shared__ float lds_scale[64];
    __shared__ float lds_shift[64];
    int cnt = *ccount_c;
    if ((int)blockIdx.x * 4 >= cnt) return;
    int lane = threadIdx.x & 63;
    int wave = threadIdx.x >> 6;
    if (threadIdx.x < 64) {
        float s = 0.f, q = 0.f;
        #pragma unroll
        for (int sh = 0; sh < NSHADOW; sh++) {
            s += bnacc[sh * 128 + threadIdx.x];
            q += bnacc[sh * 128 + 64 + threadIdx.x];
        }
        float fc = fmaxf((float)cnt, 1.f);
        float mean = s / fc;
        float var = q / fc - mean * mean;
        float sc = g1[threadIdx.x] * rsqrtf(var + BN_EPS);
        lds_scale[threadIdx.x] = sc;
        lds_shift[threadIdx.x] = be1[threadIdx.x] - mean * sc;
    }
    __syncthreads();
    int idx = blockIdx.x * 4 + wave;
    if (idx >= cnt) return;
    float h = h1buf[idx * 64 + lane];
    float a = fmaxf(h * lds_scale[lane] + lds_shift[lane], 0.f);
    float s = b2[lane];
    #pragma unroll
    for (int j = 0; j < 64; j++) {
        s += __shfl(a, j) * W2[j * 64 + lane];
    }
    int node = clist_c[idx];
    xw[node * 64 + lane] = s;
}

// ---------------- pooling (batch is sorted) ----------------
__global__ void k_pool(const float* __restrict__ xw, const int* __restrict__ batch,
                       float* __restrict__ z, int t) {
    const int CHUNK = 256;
    int lane = threadIdx.x & 63;
    int wg = (blockIdx.x * blockDim.x + threadIdx.x) >> 6;
    int lo = wg * CHUNK;
    if (lo >= NN) return;
    int hi = min(lo + CHUNK, NN);
    float acc = 0.f;
    int curg = batch[lo];
    for (int n = lo; n < hi; n++) {
        int g = batch[n];
        if (g != curg) {
            atomicAdd(&z[curg * (HH * LL) + t * HH + lane], acc);
            acc = 0.f;
            curg = g;
        }
        acc += xw[n * 64 + lane];
    }
    atomicAdd(&z[curg * (HH * LL) + t * HH + lane], acc);
}

// ---------------- final MLP (single block) ----------------
__global__ __launch_bounds__(256) void k_final(
    const float* __restrict__ z, const float* __restrict__ Wp1,
    const float* __restrict__ bp1, const float* __restrict__ gp,
    const float* __restrict__ bep, const float* __restrict__ Wp2,
    const float* __restrict__ bp2, float* __restrict__ out) {
    __shared__ float lds[64 * 64];
    __shared__ float sscale[64];
    __shared__ float sshift[64];
    int tid = threadIdx.x;
    // stage 1: h = z @ Wp1 + bp1  (64x192 @ 192x64)
    for (int i = tid; i < 64 * 64; i += 256) {
        int g = i >> 6, k = i & 63;
        float s = bp1[k];
        for (int j = 0; j < HH * LL; j++) s += z[g * (HH * LL) + j] * Wp1[j * 64 + k];
        lds[i] = s;
    }
    __syncthreads();
    // stage 2: BN over all 64 rows
    if (tid < 64) {
        float s = 0.f, q = 0.f;
        for (int g = 0; g < 64; g++) { float v = lds[g * 64 + tid]; s += v; q += v * v; }
        float mean = s / 64.f;
        float var = q / 64.f - mean * mean;
        float sc = gp[tid] * rsqrtf(var + BN_EPS);
        sscale[tid] = sc;
        sshift[tid] = bep[tid] - mean * sc;
    }
    __syncthreads();
    // stage 3: relu(bn) in place
    for (int i = tid; i < 64 * 64; i += 256) {
        int k = i & 63;
        lds[i] = fmaxf(lds[i] * sscale[k] + sshift[k], 0.f);
    }
    __syncthreads();
    // stage 4: out = h @ Wp2 + bp2
    for (int i = tid; i < 64 * 64; i += 256) {
        int g = i >> 6, o = i & 63;
        float s = bp2[o];
        for (int k = 0; k < 64; k++) s += lds[g * 64 + k] * Wp2[k * 64 + o];
        out[g * 64 + o] = s;
    }
}

// ---------------- launch ----------------
extern "C" void kernel_launch(void* const* d_in, const int* in_sizes, int n_in,
                              void* d_out, int out_size, void* d_ws, size_t ws_size,
                              hipStream_t stream) {
    const float* x_in = (const float*)d_in[0];
    const int* labels = (const int*)d_in[1];
    const int* esrc = (const int*)d_in[2];        // edge_index row 0 (src), int32
    const int* edst = esrc + EE;                  // edge_index row 1 (dst)
    const int* batch = (const int*)d_in[3];       // int32
    const float* W1 = (const float*)d_in[4];
    const float* b1 = (const float*)d_in[5];
    const float* g1 = (const float*)d_in[6];
    const float* be1 = (const float*)d_in[7];
    const float* W2 = (const float*)d_in[8];
    const float* b2 = (const float*)d_in[9];
    const float* Wp1 = (const float*)d_in[10];
    const float* bp1 = (const float*)d_in[11];
    const float* gp = (const float*)d_in[12];
    const float* bep = (const float*)d_in[13];
    const float* Wp2 = (const float*)d_in[14];
    const float* bp2 = (const float*)d_in[15];
    float* out = (float*)d_out;

    char* p = (char*)d_ws;
    auto carve = [&](size_t bytes) -> void* {
        void* r = (void*)p;
        p += (bytes + 255) & ~(size_t)255;
        return r;
    };
    // ---- zeroed region (one memset) ----
    float* bnacc = (float*)carve((size_t)LL * CC * NSHADOW * 128 * 4);  // 98304 B
    float* z     = (float*)carve((size_t)GG * HH * LL * 4);             // 49152 B
    int*   deg   = (int*)carve((size_t)NN * 4);
    int*   ccount= (int*)carve(4 * 4);
    size_t zero_bytes = (size_t)(p - (char*)d_ws);
    // ---- rest ----
    float* xw     = (float*)carve((size_t)NN * 64 * 4);
    float* h1buf  = (float*)carve((size_t)NN * 64 * 4);
    int*   rowptr = (int*)carve((size_t)(NN + 1) * 4);
    int*   cursor = (int*)carve((size_t)NN * 4);
    int*   adj    = (int*)carve((size_t)EE * 4);
    int*   clist  = (int*)carve((size_t)CC * NN * 4);

    hipMemsetAsync(d_ws, 0, zero_bytes, stream);
    hipMemcpyAsync(xw, x_in, (size_t)NN * 64 * 4, hipMemcpyDeviceToDevice, stream);

    k_deg<<<(EE + 255) / 256, 256, 0, stream>>>(edst, deg);
    k_clist<<<(NN + 255) / 256, 256, 0, stream>>>(labels, ccount, clist);
    k_scan<<<1, 1024, 0, stream>>>(deg, rowptr, cursor);
    k_fill<<<(EE + 255) / 256, 256, 0, stream>>>(esrc, edst, cursor, adj);

    int gin_blocks = (NN + 3) / 4;  // 1 node per wave, 4 waves per block
    for (int t = 0; t < LL; t++) {
        for (int c = 0; c < CC; c++) {
            int tc = t * CC + c;
            k_gin_a<<<gin_blocks, 256, 0, stream>>>(
                xw, adj, rowptr, clist + c * NN, ccount + c,
                W1 + (size_t)tc * 64 * 64, b1 + (size_t)tc * 64, h1buf,
                bnacc + (size_t)tc * NSHADOW * 128);
            k_gin_c<<<gin_blocks, 256, 0, stream>>>(
                xw, clist + c * NN, ccount + c,
                g1 + (size_t)tc * 64, be1 + (size_t)tc * 64,
                W2 + (size_t)tc * 64 * 64, b2 + (size_t)tc * 64, h1buf,
                bnacc + (size_t)tc * NSHADOW * 128);
        }
        int pool_waves = (NN + 255) / 256;
        int pool_blocks = (pool_waves * 64 + 255) / 256;
        k_pool<<<pool_blocks, 256, 0, stream>>>(xw, batch, z, t);
    }
    k_final<<<1, 256, 0, stream>>>(z, Wp1, bp1, gp, bep, Wp2, bp2, out);
}

// Round 3
// 1230.296 us; speedup vs baseline: 1.2055x; 1.2055x over previous
//
#include <hip/hip_runtime.h>
#include <hip/hip_bf16.h>

#define NN 50000
#define EE 800000
#define GG 64
#define LL 3
#define CC 4
#define HH 64
#define BN_EPS 1e-5f
#define NSHADOW 16
#define NB 196           // ceil(NN/256) histogram blocks
#define GIN_BLOCKS 1024  // grid-stride GIN kernels

// NOTE: harness passes ALL integer inputs as int32 (edge_index/batch included).

// ---------------- setup kernels ----------------

__global__ void k_deg(const int* __restrict__ dst, int* __restrict__ deg) {
    int e = blockIdx.x * blockDim.x + threadIdx.x;
    if (e < EE) atomicAdd(&deg[dst[e]], 1);
}

// per-block histogram of cluster labels (LDS atomics only)
__global__ void k_hist(const int* __restrict__ labels, int* __restrict__ blockcnt) {
    __shared__ int cnt[CC];
    int tid = threadIdx.x;
    if (tid < CC) cnt[tid] = 0;
    __syncthreads();
    int i = blockIdx.x * 256 + tid;
    if (i < NN) atomicAdd(&cnt[labels[i]], 1);
    __syncthreads();
    if (tid < CC) blockcnt[tid * NB + blockIdx.x] = cnt[tid];
}

// exclusive scan of per-block counts within each cluster; one block of 256 threads
__global__ __launch_bounds__(256) void k_cscan(const int* __restrict__ blockcnt,
                                               int* __restrict__ coffs,
                                               int* __restrict__ ccount) {
    __shared__ int s[CC][256];
    int t = threadIdx.x;
    int own[CC];
    for (int c = 0; c < CC; c++) {
        own[c] = (t < NB) ? blockcnt[c * NB + t] : 0;
        s[c][t] = own[c];
    }
    __syncthreads();
    for (int off = 1; off < 256; off <<= 1) {
        int v[CC];
        for (int c = 0; c < CC; c++) v[c] = (t >= off) ? s[c][t - off] : 0;
        __syncthreads();
        for (int c = 0; c < CC; c++) s[c][t] += v[c];
        __syncthreads();
    }
    if (t < NB)
        for (int c = 0; c < CC; c++) coffs[c * NB + t] = s[c][t] - own[c];
    if (t == 0)
        for (int c = 0; c < CC; c++) ccount[c] = s[c][255];
}

__global__ void k_cfill(const int* __restrict__ labels, const int* __restrict__ coffs,
                        int* __restrict__ clist) {
    __shared__ int pos[CC];
    int tid = threadIdx.x;
    if (tid < CC) pos[tid] = coffs[tid * NB + blockIdx.x];
    __syncthreads();
    int i = blockIdx.x * 256 + tid;
    if (i < NN) {
        int c = labels[i];
        int p = atomicAdd(&pos[c], 1);
        clist[c * NN + p] = i;
    }
}

__global__ __launch_bounds__(1024) void k_scan(const int* __restrict__ deg,
                                               int* __restrict__ rowptr,
                                               int* __restrict__ cursor) {
    __shared__ int tot[1024];
    int t = threadIdx.x;
    const int CH = (NN + 1023) / 1024;  // 49
    int lo = t * CH;
    int hi = min(lo + CH, NN);
    int s = 0;
    for (int i = lo; i < hi; i++) s += deg[i];
    tot[t] = s;
    __syncthreads();
    // Hillis-Steele inclusive scan over 1024 partials
    for (int off = 1; off < 1024; off <<= 1) {
        int v = (t >= off) ? tot[t - off] : 0;
        __syncthreads();
        tot[t] += v;
        __syncthreads();
    }
    int run = tot[t] - s;  // exclusive base
    for (int i = lo; i < hi; i++) { rowptr[i] = run; cursor[i] = run; run += deg[i]; }
    if (t == 1023) rowptr[NN] = tot[1023];  // == EE
}

__global__ void k_fill(const int* __restrict__ src, const int* __restrict__ dst,
                       int* __restrict__ cursor, int* __restrict__ adj) {
    int e = blockIdx.x * blockDim.x + threadIdx.x;
    if (e < EE) {
        int d = dst[e];
        int pos = atomicAdd(&cursor[d], 1);
        adj[pos] = src[e];
    }
}

// ---------------- per-(t,c) kernels ----------------
// Kernel A: agg (CSR gather) + h = agg + x, h1 = h@W1 + b1; store h1; accumulate BN stats.
// grid-stride over cluster members; 1 node per wave.
__global__ __launch_bounds__(256) void k_gin_a(
    const float* __restrict__ xw, const int* __restrict__ adj,
    const int* __restrict__ rowptr, const int* __restrict__ clist_c,
    const int* __restrict__ ccount_c, const float* __restrict__ W1,
    const float* __restrict__ b1, float* __restrict__ h1buf,
    float* __restrict__ bnacc) {
    __shared__ float lds_bn[128];
    int cnt = *ccount_c;
    int lane = threadIdx.x & 63;
    int wave = threadIdx.x >> 6;
    if (threadIdx.x < 128) lds_bn[threadIdx.x] = 0.f;
    __syncthreads();
    int nwaves = gridDim.x * 4;
    for (int idx = blockIdx.x * 4 + wave; idx < cnt; idx += nwaves) {
        int node = clist_c[idx];
        int rb = rowptr[node], re = rowptr[node + 1];
        float a0 = xw[node * 64 + lane], a1 = 0.f, a2 = 0.f, a3 = 0.f;
        int base = rb;
        int remaining = re - rb;
        while (remaining > 0) {
            int take = min(remaining, 64);
            // coalesced prefetch of up to 64 neighbor indices for this wave
            int nb = adj[base + min(lane, take - 1)];
            int j = 0;
            for (; j + 4 <= take; j += 4) {
                int n0 = __shfl(nb, j + 0);
                int n1 = __shfl(nb, j + 1);
                int n2 = __shfl(nb, j + 2);
                int n3 = __shfl(nb, j + 3);
                a0 += xw[n0 * 64 + lane];
                a1 += xw[n1 * 64 + lane];
                a2 += xw[n2 * 64 + lane];
                a3 += xw[n3 * 64 + lane];
            }
            for (; j < take; j++) {
                int n = __shfl(nb, j);
                a0 += xw[n * 64 + lane];
            }
            base += take;
            remaining -= take;
        }
        float acc = (a0 + a1) + (a2 + a3);
        // h1[lane] = b1[lane] + sum_j h[j] * W1[j][lane]  (h[j] broadcast via shfl)
        float s = b1[lane];
        #pragma unroll
        for (int j = 0; j < 64; j++) {
            s += __shfl(acc, j) * W1[j * 64 + lane];
        }
        h1buf[idx * 64 + lane] = s;
        atomicAdd(&lds_bn[lane], s);
        atomicAdd(&lds_bn[64 + lane], s * s);
    }
    __syncthreads();
    if (threadIdx.x < 128) {
        atomicAdd(&bnacc[(blockIdx.x & (NSHADOW - 1)) * 128 + threadIdx.x], lds_bn[threadIdx.x]);
    }
}

// Kernel C: scale/shift from BN stats; h1n = relu(bn(h1)); h2 = h1n@W2 + b2; x[node] = h2.
__global__ __launch_bounds__(256) void k_gin_c(
    float* __restrict__ xw, const int* __restrict__ clist_c,
    const int* __restrict__ ccount_c, const float* __restrict__ g1,
    const float* __restrict__ be1, const float* __restrict__ W2,
    const float* __restrict__ b2, const float* __restrict__ h1buf,
    const float* __restrict__ bnacc) {
    __shared__ float lds_scale[64];
    __shared__ float lds_shift[64];
    int cnt = *ccount_c;
    int lane = threadIdx.x & 63;
    int wave = threadIdx.x >> 6;
    if (threadIdx.x < 64) {
        float s = 0.f, q = 0.f;
        #pragma unroll
        for (int sh = 0; sh < NSHADOW; sh++) {
            s += bnacc[sh * 128 + threadIdx.x];
            q += bnacc[sh * 128 + 64 + threadIdx.x];
        }
        float fc = fmaxf((float)cnt, 1.f);
        float mean = s / fc;
        float var = q / fc - mean * mean;
        float sc = g1[threadIdx.x] * rsqrtf(var + BN_EPS);
        lds_scale[threadIdx.x] = sc;
        lds_shift[threadIdx.x] = be1[threadIdx.x] - mean * sc;
    }
    __syncthreads();
    int nwaves = gridDim.x * 4;
    for (int idx = blockIdx.x * 4 + wave; idx < cnt; idx += nwaves) {
        float h = h1buf[idx * 64 + lane];
        float a = fmaxf(h * lds_scale[lane] + lds_shift[lane], 0.f);
        float s = b2[lane];
        #pragma unroll
        for (int j = 0; j < 64; j++) {
            s += __shfl(a, j) * W2[j * 64 + lane];
        }
        int node = clist_c[idx];
        xw[node * 64 + lane] = s;
    }
}

// ---------------- pooling (batch is sorted) ----------------
__global__ void k_pool(const float* __restrict__ xw, const int* __restrict__ batch,
                       float* __restrict__ z, int t) {
    const int CHUNK = 256;
    int lane = threadIdx.x & 63;
    int wg = (blockIdx.x * blockDim.x + threadIdx.x) >> 6;
    int lo = wg * CHUNK;
    if (lo >= NN) return;
    int hi = min(lo + CHUNK, NN);
    float acc = 0.f;
    int curg = batch[lo];
    for (int n = lo; n < hi; n++) {
        int g = batch[n];
        if (g != curg) {
            atomicAdd(&z[curg * (HH * LL) + t * HH + lane], acc);
            acc = 0.f;
            curg = g;
        }
        acc += xw[n * 64 + lane];
    }
    atomicAdd(&z[curg * (HH * LL) + t * HH + lane], acc);
}

// ---------------- final MLP (single block) ----------------
__global__ __launch_bounds__(256) void k_final(
    const float* __restrict__ z, const float* __restrict__ Wp1,
    const float* __restrict__ bp1, const float* __restrict__ gp,
    const float* __restrict__ bep, const float* __restrict__ Wp2,
    const float* __restrict__ bp2, float* __restrict__ out) {
    __shared__ float lds[64 * 64];
    __shared__ float sscale[64];
    __shared__ float sshift[64];
    int tid = threadIdx.x;
    // stage 1: h = z @ Wp1 + bp1  (64x192 @ 192x64)
    for (int i = tid; i < 64 * 64; i += 256) {
        int g = i >> 6, k = i & 63;
        float s = bp1[k];
        #pragma unroll 8
        for (int j = 0; j < HH * LL; j++) s += z[g * (HH * LL) + j] * Wp1[j * 64 + k];
        lds[i] = s;
    }
    __syncthreads();
    // stage 2: BN over all 64 rows
    if (tid < 64) {
        float s = 0.f, q = 0.f;
        for (int g = 0; g < 64; g++) { float v = lds[g * 64 + tid]; s += v; q += v * v; }
        float mean = s / 64.f;
        float var = q / 64.f - mean * mean;
        float sc = gp[tid] * rsqrtf(var + BN_EPS);
        sscale[tid] = sc;
        sshift[tid] = bep[tid] - mean * sc;
    }
    __syncthreads();
    // stage 3: relu(bn) in place
    for (int i = tid; i < 64 * 64; i += 256) {
        int k = i & 63;
        lds[i] = fmaxf(lds[i] * sscale[k] + sshift[k], 0.f);
    }
    __syncthreads();
    // stage 4: out = h @ Wp2 + bp2
    for (int i = tid; i < 64 * 64; i += 256) {
        int g = i >> 6, o = i & 63;
        float s = bp2[o];
        #pragma unroll 8
        for (int k = 0; k < 64; k++) s += lds[g * 64 + k] * Wp2[k * 64 + o];
        out[g * 64 + o] = s;
    }
}

// ---------------- launch ----------------
extern "C" void kernel_launch(void* const* d_in, const int* in_sizes, int n_in,
                              void* d_out, int out_size, void* d_ws, size_t ws_size,
                              hipStream_t stream) {
    const float* x_in = (const float*)d_in[0];
    const int* labels = (const int*)d_in[1];
    const int* esrc = (const int*)d_in[2];        // edge_index row 0 (src), int32
    const int* edst = esrc + EE;                  // edge_index row 1 (dst)
    const int* batch = (const int*)d_in[3];       // int32
    const float* W1 = (const float*)d_in[4];
    const float* b1 = (const float*)d_in[5];
    const float* g1 = (const float*)d_in[6];
    const float* be1 = (const float*)d_in[7];
    const float* W2 = (const float*)d_in[8];
    const float* b2 = (const float*)d_in[9];
    const float* Wp1 = (const float*)d_in[10];
    const float* bp1 = (const float*)d_in[11];
    const float* gp = (const float*)d_in[12];
    const float* bep = (const float*)d_in[13];
    const float* Wp2 = (const float*)d_in[14];
    const float* bp2 = (const float*)d_in[15];
    float* out = (float*)d_out;

    char* p = (char*)d_ws;
    auto carve = [&](size_t bytes) -> void* {
        void* r = (void*)p;
        p += (bytes + 255) & ~(size_t)255;
        return r;
    };
    // ---- zeroed region (one memset) ----
    float* bnacc = (float*)carve((size_t)LL * CC * NSHADOW * 128 * 4);
    float* z     = (float*)carve((size_t)GG * HH * LL * 4);
    int*   deg   = (int*)carve((size_t)NN * 4);
    size_t zero_bytes = (size_t)(p - (char*)d_ws);
    // ---- rest ----
    int*   ccount  = (int*)carve(CC * 4);
    int*   blockcnt= (int*)carve((size_t)CC * NB * 4);
    int*   coffs   = (int*)carve((size_t)CC * NB * 4);
    float* xw      = (float*)carve((size_t)NN * 64 * 4);
    float* h1buf   = (float*)carve((size_t)NN * 64 * 4);
    int*   rowptr  = (int*)carve((size_t)(NN + 1) * 4);
    int*   cursor  = (int*)carve((size_t)NN * 4);
    int*   adj     = (int*)carve((size_t)EE * 4);
    int*   clist   = (int*)carve((size_t)CC * NN * 4);

    hipMemsetAsync(d_ws, 0, zero_bytes, stream);
    hipMemcpyAsync(xw, x_in, (size_t)NN * 64 * 4, hipMemcpyDeviceToDevice, stream);

    k_deg<<<(EE + 255) / 256, 256, 0, stream>>>(edst, deg);
    k_hist<<<NB, 256, 0, stream>>>(labels, blockcnt);
    k_cscan<<<1, 256, 0, stream>>>(blockcnt, coffs, ccount);
    k_cfill<<<NB, 256, 0, stream>>>(labels, coffs, clist);
    k_scan<<<1, 1024, 0, stream>>>(deg, rowptr, cursor);
    k_fill<<<(EE + 255) / 256, 256, 0, stream>>>(esrc, edst, cursor, adj);

    for (int t = 0; t < LL; t++) {
        for (int c = 0; c < CC; c++) {
            int tc = t * CC + c;
            k_gin_a<<<GIN_BLOCKS, 256, 0, stream>>>(
                xw, adj, rowptr, clist + c * NN, ccount + c,
                W1 + (size_t)tc * 64 * 64, b1 + (size_t)tc * 64, h1buf,
                bnacc + (size_t)tc * NSHADOW * 128);
            k_gin_c<<<GIN_BLOCKS, 256, 0, stream>>>(
                xw, clist + c * NN, ccount + c,
                g1 + (size_t)tc * 64, be1 + (size_t)tc * 64,
                W2 + (size_t)tc * 64 * 64, b2 + (size_t)tc * 64, h1buf,
                bnacc + (size_t)tc * NSHADOW * 128);
        }
        int pool_waves = (NN + 255) / 256;
        int pool_blocks = (pool_waves * 64 + 255) / 256;
        k_pool<<<pool_blocks, 256, 0, stream>>>(xw, batch, z, t);
    }
    k_final<<<1, 256, 0, stream>>>(z, Wp1, bp1, gp, bep, Wp2, bp2, out);
}